// Round 1
// baseline (549.652 us; speedup 1.0000x reference)
//
#include <hip/hip_runtime.h>
#include <stdint.h>

typedef __attribute__((ext_vector_type(8))) short short8;
typedef __attribute__((ext_vector_type(4))) float floatx4;

// ---------- helpers ----------
__device__ __forceinline__ unsigned short f2b(float f) {
    union { float f; uint32_t u; } v; v.f = f;
    uint32_t u = v.u;
    return (unsigned short)((u + 0x7FFFu + ((u >> 16) & 1u)) >> 16);  // RNE
}

// pack two fp32 -> two bf16 (round-half-up; bias negligible at threshold)
__device__ __forceinline__ uint32_t pk2(float a, float b) {
    union { float f; uint32_t u; } x, y; x.f = a; y.f = b;
    uint32_t ua = x.u + 0x8000u, ub = y.u + 0x8000u;
    return (ua >> 16) | (ub & 0xFFFF0000u);
}

__device__ __forceinline__ void async16(const void* g, void* l) {
    __builtin_amdgcn_global_load_lds(
        (const __attribute__((address_space(1))) void*)g,
        (__attribute__((address_space(3))) void*)l, 16, 0, 0);
}

// ---------- kernel 1: L2-normalize rows, emit bf16 ----------
__global__ void norm_kernel(const float* __restrict__ in,
                            unsigned short* __restrict__ xb, int D) {
    int b = blockIdx.x, t = threadIdx.x;
    const float* row = in + (size_t)b * D;
    float ss = 0.f;
    for (int i = t * 4; i < D; i += 1024) {
        float4 v = *(const float4*)(row + i);
        ss += v.x * v.x + v.y * v.y + v.z * v.z + v.w * v.w;
    }
    for (int off = 32; off > 0; off >>= 1) ss += __shfl_down(ss, off);
    __shared__ float wsum[4];
    __shared__ float rn_sh;
    if ((t & 63) == 0) wsum[t >> 6] = ss;
    __syncthreads();
    if (t == 0) rn_sh = rsqrtf(wsum[0] + wsum[1] + wsum[2] + wsum[3]);
    __syncthreads();
    float rn = rn_sh;
    unsigned short* orow = xb + (size_t)b * D;
    for (int i = t * 4; i < D; i += 1024) {
        float4 v = *(const float4*)(row + i);
        ushort4 o;
        o.x = f2b(v.x * rn); o.y = f2b(v.y * rn);
        o.z = f2b(v.z * rn); o.w = f2b(v.w * rn);
        *(ushort4*)(orow + i) = o;
    }
}

// ---------- kernel 2: fused GEMM (software-pipelined, double-buffered) ----
// BM=256 (full batch, B-matrix read exactly once), BN=64, BK=64.
// LDS rows are 128 B (=32 banks); 16 B chunk c of row r stored at slot
// c ^ (r&7)  ->  every b128 read/write phase is <=2-way (free).
// Pipeline: at iter kt, issue A global_load_lds + B global->reg loads for
// kt+1 BEFORE computing tile kt; pack+ds_write B after the MFMAs; ONE
// barrier per K-step.  Load latency (B from HBM ~900cy) hides under the
// ~1500cy ds_read+MFMA phase instead of serializing with it.
#define BKk 64
__global__ __launch_bounds__(256, 2)
void gemm_kernel(const unsigned short* __restrict__ xb,
                 const float* __restrict__ featB,
                 const float* __restrict__ centB,
                 const int* __restrict__ targets,
                 float* __restrict__ S, float* __restrict__ pos,
                 float* __restrict__ km,
                 int D, int K, int nbF) {
    __shared__ __align__(16) unsigned short Alds[2][256 * BKk];  // 64 KB
    __shared__ __align__(16) unsigned short Blds[2][64 * BKk];   // 16 KB

    const int t = threadIdx.x;
    const int w = t >> 6, l = t & 63;
    const bool isFeat = ((int)blockIdx.x < nbF);
    const int n0 = (isFeat ? (int)blockIdx.x : ((int)blockIdx.x - nbF)) * 64;
    const float* Bsrc = isFeat ? featB : centB;

    floatx4 acc[4][4];
#pragma unroll
    for (int ti = 0; ti < 4; ++ti)
#pragma unroll
        for (int tj = 0; tj < 4; ++tj)
            acc[ti][tj] = (floatx4){0.f, 0.f, 0.f, 0.f};

    const int kIters = D / BKk;                       // 32
    const int brow = t >> 2, bq = t & 3;              // B staging: 4 thr/row
    const float* bg0 = Bsrc + (size_t)(n0 + brow) * D + bq * 16;
    const int bc0 = ((bq * 2) ^ (brow & 7)) * 16;     // swizzled chunk slots
    const int bc1 = ((bq * 2 + 1) ^ (brow & 7)) * 16;
    const char* xbB = (const char*)xb;

    // issue the 8 direct-to-LDS A loads for tile ktn into buffer nb
    auto stageA = [&](int nb, int ktn) {
#pragma unroll
        for (int j = 0; j < 8; ++j) {
            int slin = j * 256 + t;                   // 16 B slot index
            int r = slin >> 3;                        // A row (0..255)
            int cg = (slin & 7) ^ (r & 7);            // global chunk for slot
            async16(xbB + (size_t)r * (D * 2) + (size_t)ktn * (BKk * 2) + cg * 16,
                    (char*)(&Alds[nb][0]) + slin * 16);
        }
    };

    // 2 sub-steps of K=32, 16 MFMA each, reading buffer cb
    auto compute = [&](int cb) {
        const char* Ab = (const char*)(&Alds[cb][0]);
        const char* Bb = (const char*)(&Blds[cb][0]);
#pragma unroll
        for (int s = 0; s < 2; ++s) {
            short8 aF[4], bF[4];
#pragma unroll
            for (int ti = 0; ti < 4; ++ti) {
                int R = w * 64 + ti * 16 + (l & 15);
                int g = s * 4 + (l >> 4);
                aF[ti] = *(const short8*)(Ab + R * 128 + ((g ^ (R & 7)) * 16));
            }
#pragma unroll
            for (int tj = 0; tj < 4; ++tj) {
                int Rn = tj * 16 + (l & 15);
                int g = s * 4 + (l >> 4);
                bF[tj] = *(const short8*)(Bb + Rn * 128 + ((g ^ (Rn & 7)) * 16));
            }
#pragma unroll
            for (int ti = 0; ti < 4; ++ti)
#pragma unroll
                for (int tj = 0; tj < 4; ++tj)
                    acc[ti][tj] = __builtin_amdgcn_mfma_f32_16x16x32_bf16(
                        aF[ti], bF[tj], acc[ti][tj], 0, 0, 0);
        }
    };

    // ---- prologue: stage tile 0 into buffer 0
    stageA(0, 0);
    {
        const float* bg = bg0;
        float4 f0 = *(const float4*)(bg);
        float4 f1 = *(const float4*)(bg + 4);
        float4 f2 = *(const float4*)(bg + 8);
        float4 f3 = *(const float4*)(bg + 12);
        uint4 p0, p1;
        p0.x = pk2(f0.x, f0.y); p0.y = pk2(f0.z, f0.w);
        p0.z = pk2(f1.x, f1.y); p0.w = pk2(f1.z, f1.w);
        p1.x = pk2(f2.x, f2.y); p1.y = pk2(f2.z, f2.w);
        p1.z = pk2(f3.x, f3.y); p1.w = pk2(f3.z, f3.w);
        char* bb = (char*)(&Blds[0][0]) + brow * 128;
        *(uint4*)(bb + bc0) = p0;
        *(uint4*)(bb + bc1) = p1;
    }
    __syncthreads();   // vmcnt(0)+lgkmcnt(0): tile 0 visible

    // ---- pipelined main loop: one barrier per K-step
    for (int kt = 0; kt < kIters - 1; ++kt) {
        const int cb = kt & 1, nb = cb ^ 1;
        // issue next tile's loads first (latency hides under compute)
        stageA(nb, kt + 1);
        const float* bg = bg0 + (kt + 1) * BKk;
        float4 f0 = *(const float4*)(bg);
        float4 f1 = *(const float4*)(bg + 4);
        float4 f2 = *(const float4*)(bg + 8);
        float4 f3 = *(const float4*)(bg + 12);

        compute(cb);

        // B regs have had the whole MFMA phase to land; pack + write
        uint4 p0, p1;
        p0.x = pk2(f0.x, f0.y); p0.y = pk2(f0.z, f0.w);
        p0.z = pk2(f1.x, f1.y); p0.w = pk2(f1.z, f1.w);
        p1.x = pk2(f2.x, f2.y); p1.y = pk2(f2.z, f2.w);
        p1.z = pk2(f3.x, f3.y); p1.w = pk2(f3.z, f3.w);
        char* bb = (char*)(&Blds[nb][0]) + brow * 128;
        *(uint4*)(bb + bc0) = p0;
        *(uint4*)(bb + bc1) = p1;
        __syncthreads();   // publishes buffer nb; all reads of cb are done
    }
    compute((kIters - 1) & 1);

    // epilogue.  C/D layout: col = l&15, row = (l>>4)*4 + reg  [m89-verified]
    if (isFeat) {
#pragma unroll
        for (int ti = 0; ti < 4; ++ti) {
#pragma unroll
            for (int r = 0; r < 4; ++r) {
                int row = w * 64 + ti * 16 + ((l >> 4) << 2) + r;
                int tr = targets[row];
                int col0 = n0 + (l & 15);
                float e = 0.f;
#pragma unroll
                for (int tj = 0; tj < 4; ++tj) {
                    float c = acc[ti][tj][r];
                    e += __expf(c * 20.0f);            // |c|<=~1 -> safe
                    if (tr == col0 + tj * 16) pos[row] = c;
                }
                e += __shfl_xor(e, 1); e += __shfl_xor(e, 2);
                e += __shfl_xor(e, 4); e += __shfl_xor(e, 8);
                if ((l & 15) == 0) atomicAdd(&S[row], e);
            }
        }
    } else {
#pragma unroll
        for (int ti = 0; ti < 4; ++ti) {
#pragma unroll
            for (int r = 0; r < 4; ++r) {
                int row = w * 64 + ti * 16 + ((l >> 4) << 2) + r;
                size_t base = (size_t)row * K + n0 + (l & 15);
#pragma unroll
                for (int tj = 0; tj < 4; ++tj)
                    km[base + tj * 16] = acc[ti][tj][r];
            }
        }
    }
}

// ---------- kernel 3: per-row top-neg_size (register-resident selection) ----
// Thread t owns elements k*256+t (k=0..31) in registers.  Per extraction:
// shuffle-reduce block argmax, owner lane clears + rescans locally.
__global__ __launch_bounds__(256, 4)
void topk_kernel(const float* __restrict__ kmr,
                 const int* __restrict__ pids,
                 const int* __restrict__ idxs,
                 const int* __restrict__ negsz,
                 float* __restrict__ topv, int K) {
    int b = blockIdx.x, t = threadIdx.x;
    int w = t >> 6, l = t & 63;
    const float* row = kmr + (size_t)b * K;
    float v[32];
#pragma unroll
    for (int k = 0; k < 32; ++k) v[k] = row[k * 256 + t];
    int gi = pids[idxs[b]];          // masked position (never top-20 in ref)
    if ((gi & 255) == t) {
        int kk = gi >> 8;
#pragma unroll
        for (int k = 0; k < 32; ++k) if (k == kk) v[k] = -1e30f;
    }
    float bv = v[0]; int bk = 0;
#pragma unroll
    for (int k = 1; k < 32; ++k) if (v[k] > bv) { bv = v[k]; bk = k; }

    __shared__ float rv[4];
    __shared__ int rg[4];
    int ns = *negsz; if (ns > 32) ns = 32;
    for (int j = 0; j < ns; ++j) {
        float mv = bv; int mg = bk * 256 + t;
#pragma unroll
        for (int off = 1; off < 64; off <<= 1) {
            float ov = __shfl_xor(mv, off);
            int og = __shfl_xor(mg, off);
            if (ov > mv) { mv = ov; mg = og; }
        }
        if (l == 0) { rv[w] = mv; rg[w] = mg; }
        __syncthreads();
        float gv = rv[0]; int gg = rg[0];
#pragma unroll
        for (int ww = 1; ww < 4; ++ww)
            if (rv[ww] > gv) { gv = rv[ww]; gg = rg[ww]; }
        if (t == 0) topv[b * 32 + j] = gv;
        if ((gg & 255) == t) {
            int kk = gg >> 8;
#pragma unroll
            for (int k = 0; k < 32; ++k) if (k == kk) v[k] = -1e30f;
            bv = v[0]; bk = 0;
#pragma unroll
            for (int k = 1; k < 32; ++k) if (v[k] > bv) { bv = v[k]; bk = k; }
        }
        __syncthreads();
    }
}

// ---------- kernel 4: confidence mask + losses + final scalar ----------
__global__ void final_kernel(const float* __restrict__ S,
                             const float* __restrict__ pos,
                             const float* __restrict__ topv,
                             const int* __restrict__ pids,
                             const int* __restrict__ idxs,
                             const int* __restrict__ negsz,
                             float* __restrict__ out, int B) {
    __shared__ int pid_sh[256];
    __shared__ int mode_sh[16];
    __shared__ float red[256];
    int t = threadIdx.x;
    if (t < B) pid_sh[t] = pids[idxs[t]];
    __syncthreads();
    int half = B >> 1;
    int G = half / 16;
    if (t < G) {
        int bestPid = 0x7FFFFFFF, bestCnt = -1;
        for (int i = 0; i < 16; ++i) {
            int p = pid_sh[t * 16 + i];
            int c = 0;
            for (int j = 0; j < 16; ++j) c += (pid_sh[t * 16 + j] == p) ? 1 : 0;
            if (c > bestCnt || (c == bestCnt && p < bestPid)) { bestCnt = c; bestPid = p; }
        }
        mode_sh[t] = bestPid;  // ties -> smallest id == bincount().argmax()
    }
    __syncthreads();
    float contrib = 0.f;
    if (t < B) {
        int hb = (t < half) ? t : t - half;
        float mask = (pid_sh[hb] == mode_sh[hb / 16]) ? 1.f : 0.f;
        int ns = *negsz; if (ns > 32) ns = 32;
        float p20 = pos[t] * 20.0f;
        float m = p20;
        for (int j = 0; j < ns; ++j) m = fmaxf(m, topv[t * 32 + j] * 20.0f);
        float se = __expf(p20 - m);
        for (int j = 0; j < ns; ++j) se += __expf(topv[t * 32 + j] * 20.0f - m);
        float ce_neg = m + logf(se) - p20;
        float ce_main = logf(S[t]) - p20;
        contrib = (0.2f * mask * ce_neg + ce_main) / (float)B;
    }
    red[t] = contrib;
    __syncthreads();
    for (int s = 128; s > 0; s >>= 1) {
        if (t < s) red[t] += red[t + s];
        __syncthreads();
    }
    if (t == 0) out[0] = red[0];
}

// ---------- launcher ----------
extern "C" void kernel_launch(void* const* d_in, const int* in_sizes, int n_in,
                              void* d_out, int out_size, void* d_ws, size_t ws_size,
                              hipStream_t stream) {
    const float* inputs   = (const float*)d_in[0];
    const float* features = (const float*)d_in[1];
    const float* cents    = (const float*)d_in[2];
    const int*   targets  = (const int*)d_in[3];
    const int*   pids     = (const int*)d_in[4];
    const int*   idxs     = (const int*)d_in[5];
    const int*   negsz    = (const int*)d_in[6];
    float* out = (float*)d_out;

    int Bb = in_sizes[3];            // 256
    int Dd = in_sizes[0] / Bb;       // 2048
    int Nn = in_sizes[1] / Dd;       // 32768
    int Kk = in_sizes[2] / Dd;       // 8192

    char* ws = (char*)d_ws;
    unsigned short* xb = (unsigned short*)ws;
    size_t o = (size_t)Bb * Dd * 2;
    float* km   = (float*)(ws + o); o += (size_t)Bb * Kk * 4;
    float* S    = (float*)(ws + o); o += (size_t)Bb * 4;
    float* pos  = (float*)(ws + o); o += (size_t)Bb * 4;
    float* topv = (float*)(ws + o); o += (size_t)Bb * 32 * 4;

    hipMemsetAsync(S, 0, (size_t)Bb * 4, stream);
    norm_kernel<<<Bb, 256, 0, stream>>>(inputs, xb, Dd);
    int nbF = Nn / 64, nbC = Kk / 64;
    gemm_kernel<<<nbF + nbC, 256, 0, stream>>>(xb, features, cents, targets,
                                               S, pos, km, Dd, Kk, nbF);
    topk_kernel<<<Bb, 256, 0, stream>>>(km, pids, idxs, negsz, topv, Kk);
    final_kernel<<<1, 256, 0, stream>>>(S, pos, topv, pids, idxs, negsz, out, Bb);
}

// Round 2
// 526.607 us; speedup vs baseline: 1.0438x; 1.0438x over previous
//
#include <hip/hip_runtime.h>
#include <stdint.h>

typedef __attribute__((ext_vector_type(8))) short short8;
typedef __attribute__((ext_vector_type(4))) float floatx4;

// ---------- helpers ----------
__device__ __forceinline__ unsigned short f2b(float f) {
    union { float f; uint32_t u; } v; v.f = f;
    uint32_t u = v.u;
    return (unsigned short)((u + 0x7FFFu + ((u >> 16) & 1u)) >> 16);  // RNE
}

// pack two fp32 -> two bf16 (round-half-up; bias negligible at threshold)
__device__ __forceinline__ uint32_t pk2(float a, float b) {
    union { float f; uint32_t u; } x, y; x.f = a; y.f = b;
    uint32_t ua = x.u + 0x8000u, ub = y.u + 0x8000u;
    return (ua >> 16) | (ub & 0xFFFF0000u);
}

__device__ __forceinline__ void async16(const void* g, void* l) {
    __builtin_amdgcn_global_load_lds(
        (const __attribute__((address_space(1))) void*)g,
        (__attribute__((address_space(3))) void*)l, 16, 0, 0);
}

// ---------- kernel 1: L2-normalize rows, emit bf16 ----------
__global__ void norm_kernel(const float* __restrict__ in,
                            unsigned short* __restrict__ xb, int D) {
    int b = blockIdx.x, t = threadIdx.x;
    const float* row = in + (size_t)b * D;
    float ss = 0.f;
    for (int i = t * 4; i < D; i += 1024) {
        float4 v = *(const float4*)(row + i);
        ss += v.x * v.x + v.y * v.y + v.z * v.z + v.w * v.w;
    }
    for (int off = 32; off > 0; off >>= 1) ss += __shfl_down(ss, off);
    __shared__ float wsum[4];
    __shared__ float rn_sh;
    if ((t & 63) == 0) wsum[t >> 6] = ss;
    __syncthreads();
    if (t == 0) rn_sh = rsqrtf(wsum[0] + wsum[1] + wsum[2] + wsum[3]);
    __syncthreads();
    float rn = rn_sh;
    unsigned short* orow = xb + (size_t)b * D;
    for (int i = t * 4; i < D; i += 1024) {
        float4 v = *(const float4*)(row + i);
        ushort4 o;
        o.x = f2b(v.x * rn); o.y = f2b(v.y * rn);
        o.z = f2b(v.z * rn); o.w = f2b(v.w * rn);
        *(ushort4*)(orow + i) = o;
    }
}

// ---------- kernel 2: fused GEMM ----------
// BM=256 (full batch, B-matrix read exactly once), BN=32, BK=64.
// Grid = 1280 blocks = 5/CU (vs 640 = 2.5/CU at BN=64): the r0/r1
// post-mortem showed the kernel is latency-bound with OccupancyPercent 24%
// and dur scaling inversely with occupancy -> buy TLP, not pipeline depth.
// LDS rows are 128 B (=32 banks); 16 B chunk c of row r stored at slot
// c ^ (r&7)  ->  every b128 read/write 16-lane phase is <=2-way (free;
// measured SQ_LDS_BANK_CONFLICT == 0).
#define BKk 64
__global__ __launch_bounds__(256, 4)
void gemm_kernel(const unsigned short* __restrict__ xb,
                 const float* __restrict__ featB,
                 const float* __restrict__ centB,
                 const int* __restrict__ targets,
                 float* __restrict__ S, float* __restrict__ pos,
                 float* __restrict__ km,
                 int D, int K, int nbF) {
    __shared__ __align__(16) unsigned short Alds[256 * BKk];  // 32 KB
    __shared__ __align__(16) unsigned short Blds[32 * BKk];   // 4 KB

    const int t = threadIdx.x;
    const int w = t >> 6, l = t & 63;
    const bool isFeat = ((int)blockIdx.x < nbF);
    const int n0 = (isFeat ? (int)blockIdx.x : ((int)blockIdx.x - nbF)) * 32;
    const float* Bsrc = isFeat ? featB : centB;

    floatx4 acc[4][2];
#pragma unroll
    for (int ti = 0; ti < 4; ++ti)
#pragma unroll
        for (int tj = 0; tj < 2; ++tj)
            acc[ti][tj] = (floatx4){0.f, 0.f, 0.f, 0.f};

    const int kIters = D / BKk;                       // 32
    // B staging: 32 rows x 64 cols fp32 -> bf16.  8 threads/row, each
    // thread loads 8 floats and writes ONE swizzled 16 B chunk.
    const int brow = t >> 3, bq = t & 7;
    const float* bg0 = Bsrc + (size_t)(n0 + brow) * D + bq * 8;
    const int bslot = (bq ^ (brow & 7)) * 16;         // swizzled chunk slot
    const char* xbB = (const char*)xb;

    for (int kt = 0; kt < kIters; ++kt) {
        // ---- stage A: 32 KB via direct-to-LDS; swizzle folded into src addr
#pragma unroll
        for (int j = 0; j < 8; ++j) {
            int slin = j * 256 + t;                   // 16 B slot index
            int r = slin >> 3;                        // A row (0..255)
            int cg = (slin & 7) ^ (r & 7);            // global chunk for slot
            async16(xbB + (size_t)r * (D * 2) + kt * (BKk * 2) + cg * 16,
                    (char*)Alds + slin * 16);
        }
        // ---- stage B: fp32 -> bf16, one swizzled ds_write_b128 per thread
        {
            const float* bg = bg0 + kt * BKk;
            float4 f0 = *(const float4*)(bg);
            float4 f1 = *(const float4*)(bg + 4);
            uint4 p;
            p.x = pk2(f0.x, f0.y); p.y = pk2(f0.z, f0.w);
            p.z = pk2(f1.x, f1.y); p.w = pk2(f1.z, f1.w);
            *(uint4*)((char*)Blds + brow * 128 + bslot) = p;
        }
        __syncthreads();

        // ---- compute: 2 sub-steps of K=32, 8 MFMA each
#pragma unroll
        for (int s = 0; s < 2; ++s) {
            short8 aF[4], bF[2];
#pragma unroll
            for (int ti = 0; ti < 4; ++ti) {
                int R = w * 64 + ti * 16 + (l & 15);
                int g = s * 4 + (l >> 4);
                aF[ti] = *(const short8*)((const char*)Alds +
                          R * 128 + ((g ^ (R & 7)) * 16));
            }
#pragma unroll
            for (int tj = 0; tj < 2; ++tj) {
                int Rn = tj * 16 + (l & 15);
                int g = s * 4 + (l >> 4);
                bF[tj] = *(const short8*)((const char*)Blds +
                          Rn * 128 + ((g ^ (Rn & 7)) * 16));
            }
#pragma unroll
            for (int ti = 0; ti < 4; ++ti)
#pragma unroll
                for (int tj = 0; tj < 2; ++tj)
                    acc[ti][tj] = __builtin_amdgcn_mfma_f32_16x16x32_bf16(
                        aF[ti], bF[tj], acc[ti][tj], 0, 0, 0);
        }
        __syncthreads();
    }

    // epilogue.  C/D layout: col = l&15, row = (l>>4)*4 + reg  [m89-verified]
    if (isFeat) {
#pragma unroll
        for (int ti = 0; ti < 4; ++ti) {
#pragma unroll
            for (int r = 0; r < 4; ++r) {
                int row = w * 64 + ti * 16 + ((l >> 4) << 2) + r;
                int tr = targets[row];
                int col0 = n0 + (l & 15);
                float e = 0.f;
#pragma unroll
                for (int tj = 0; tj < 2; ++tj) {
                    float c = acc[ti][tj][r];
                    e += __expf(c * 20.0f);            // |c|<=~1 -> safe
                    if (tr == col0 + tj * 16) pos[row] = c;
                }
                e += __shfl_xor(e, 1); e += __shfl_xor(e, 2);
                e += __shfl_xor(e, 4); e += __shfl_xor(e, 8);
                if ((l & 15) == 0) atomicAdd(&S[row], e);
            }
        }
    } else {
#pragma unroll
        for (int ti = 0; ti < 4; ++ti) {
#pragma unroll
            for (int r = 0; r < 4; ++r) {
                int row = w * 64 + ti * 16 + ((l >> 4) << 2) + r;
                size_t base = (size_t)row * K + n0 + (l & 15);
#pragma unroll
                for (int tj = 0; tj < 2; ++tj)
                    km[base + tj * 16] = acc[ti][tj][r];
            }
        }
    }
}

// ---------- kernel 3: per-row top-neg_size (register-resident selection) ----
// Thread t owns elements k*256+t (k=0..31) in registers.  Per extraction:
// shuffle-reduce block argmax, owner lane clears + rescans locally.
__global__ __launch_bounds__(256, 4)
void topk_kernel(const float* __restrict__ kmr,
                 const int* __restrict__ pids,
                 const int* __restrict__ idxs,
                 const int* __restrict__ negsz,
                 float* __restrict__ topv, int K) {
    int b = blockIdx.x, t = threadIdx.x;
    int w = t >> 6, l = t & 63;
    const float* row = kmr + (size_t)b * K;
    float v[32];
#pragma unroll
    for (int k = 0; k < 32; ++k) v[k] = row[k * 256 + t];
    int gi = pids[idxs[b]];          // masked position (never top-20 in ref)
    if ((gi & 255) == t) {
        int kk = gi >> 8;
#pragma unroll
        for (int k = 0; k < 32; ++k) if (k == kk) v[k] = -1e30f;
    }
    float bv = v[0]; int bk = 0;
#pragma unroll
    for (int k = 1; k < 32; ++k) if (v[k] > bv) { bv = v[k]; bk = k; }

    __shared__ float rv[4];
    __shared__ int rg[4];
    int ns = *negsz; if (ns > 32) ns = 32;
    for (int j = 0; j < ns; ++j) {
        float mv = bv; int mg = bk * 256 + t;
#pragma unroll
        for (int off = 1; off < 64; off <<= 1) {
            float ov = __shfl_xor(mv, off);
            int og = __shfl_xor(mg, off);
            if (ov > mv) { mv = ov; mg = og; }
        }
        if (l == 0) { rv[w] = mv; rg[w] = mg; }
        __syncthreads();
        float gv = rv[0]; int gg = rg[0];
#pragma unroll
        for (int ww = 1; ww < 4; ++ww)
            if (rv[ww] > gv) { gv = rv[ww]; gg = rg[ww]; }
        if (t == 0) topv[b * 32 + j] = gv;
        if ((gg & 255) == t) {
            int kk = gg >> 8;
#pragma unroll
            for (int k = 0; k < 32; ++k) if (k == kk) v[k] = -1e30f;
            bv = v[0]; bk = 0;
#pragma unroll
            for (int k = 1; k < 32; ++k) if (v[k] > bv) { bv = v[k]; bk = k; }
        }
        __syncthreads();
    }
}

// ---------- kernel 4: confidence mask + losses + final scalar ----------
__global__ void final_kernel(const float* __restrict__ S,
                             const float* __restrict__ pos,
                             const float* __restrict__ topv,
                             const int* __restrict__ pids,
                             const int* __restrict__ idxs,
                             const int* __restrict__ negsz,
                             float* __restrict__ out, int B) {
    __shared__ int pid_sh[256];
    __shared__ int mode_sh[16];
    __shared__ float red[256];
    int t = threadIdx.x;
    if (t < B) pid_sh[t] = pids[idxs[t]];
    __syncthreads();
    int half = B >> 1;
    int G = half / 16;
    if (t < G) {
        int bestPid = 0x7FFFFFFF, bestCnt = -1;
        for (int i = 0; i < 16; ++i) {
            int p = pid_sh[t * 16 + i];
            int c = 0;
            for (int j = 0; j < 16; ++j) c += (pid_sh[t * 16 + j] == p) ? 1 : 0;
            if (c > bestCnt || (c == bestCnt && p < bestPid)) { bestCnt = c; bestPid = p; }
        }
        mode_sh[t] = bestPid;  // ties -> smallest id == bincount().argmax()
    }
    __syncthreads();
    float contrib = 0.f;
    if (t < B) {
        int hb = (t < half) ? t : t - half;
        float mask = (pid_sh[hb] == mode_sh[hb / 16]) ? 1.f : 0.f;
        int ns = *negsz; if (ns > 32) ns = 32;
        float p20 = pos[t] * 20.0f;
        float m = p20;
        for (int j = 0; j < ns; ++j) m = fmaxf(m, topv[t * 32 + j] * 20.0f);
        float se = __expf(p20 - m);
        for (int j = 0; j < ns; ++j) se += __expf(topv[t * 32 + j] * 20.0f - m);
        float ce_neg = m + logf(se) - p20;
        float ce_main = logf(S[t]) - p20;
        contrib = (0.2f * mask * ce_neg + ce_main) / (float)B;
    }
    red[t] = contrib;
    __syncthreads();
    for (int s = 128; s > 0; s >>= 1) {
        if (t < s) red[t] += red[t + s];
        __syncthreads();
    }
    if (t == 0) out[0] = red[0];
}

// ---------- launcher ----------
extern "C" void kernel_launch(void* const* d_in, const int* in_sizes, int n_in,
                              void* d_out, int out_size, void* d_ws, size_t ws_size,
                              hipStream_t stream) {
    const float* inputs   = (const float*)d_in[0];
    const float* features = (const float*)d_in[1];
    const float* cents    = (const float*)d_in[2];
    const int*   targets  = (const int*)d_in[3];
    const int*   pids     = (const int*)d_in[4];
    const int*   idxs     = (const int*)d_in[5];
    const int*   negsz    = (const int*)d_in[6];
    float* out = (float*)d_out;

    int Bb = in_sizes[3];            // 256
    int Dd = in_sizes[0] / Bb;       // 2048
    int Nn = in_sizes[1] / Dd;       // 32768
    int Kk = in_sizes[2] / Dd;       // 8192

    char* ws = (char*)d_ws;
    unsigned short* xb = (unsigned short*)ws;
    size_t o = (size_t)Bb * Dd * 2;
    float* km   = (float*)(ws + o); o += (size_t)Bb * Kk * 4;
    float* S    = (float*)(ws + o); o += (size_t)Bb * 4;
    float* pos  = (float*)(ws + o); o += (size_t)Bb * 4;
    float* topv = (float*)(ws + o); o += (size_t)Bb * 32 * 4;

    hipMemsetAsync(S, 0, (size_t)Bb * 4, stream);
    norm_kernel<<<Bb, 256, 0, stream>>>(inputs, xb, Dd);
    int nbF = Nn / 32, nbC = Kk / 32;
    gemm_kernel<<<nbF + nbC, 256, 0, stream>>>(xb, features, cents, targets,
                                               S, pos, km, Dd, Kk, nbF);
    topk_kernel<<<Bb, 256, 0, stream>>>(km, pids, idxs, negsz, topv, Kk);
    final_kernel<<<1, 256, 0, stream>>>(S, pos, topv, pids, idxs, negsz, out, Bb);
}